// Round 17
// baseline (596.914 us; speedup 1.0000x reference)
//
#include <hip/hip_runtime.h>
#include <hip/hip_bf16.h>

#define NN 50000
#define NE 800000

typedef short s16x8 __attribute__((ext_vector_type(8)));
typedef float f32x4 __attribute__((ext_vector_type(4)));

__device__ __forceinline__ unsigned packbf2(float a, float b) {
  __hip_bfloat162 h = __float22bfloat162_rn(make_float2(a, b));
  return *reinterpret_cast<unsigned*>(&h);
}
__device__ __forceinline__ unsigned short bf16rn(float x) {
  return (unsigned short)(packbf2(x, x) & 0xffffu);
}

// ---------------- zero counts ----------------
__global__ __launch_bounds__(256) void zero_counts(int* __restrict__ counts) {
  const int i = blockIdx.x * 256 + threadIdx.x;
  if (i < NN) counts[i] = 0;
}

// ---------------- fused: CSR count (3125 blocks) + fold_w (64) + pack_w (96) ----------------
__global__ __launch_bounds__(256) void count_fold_pack(
    const int* __restrict__ ei, int* __restrict__ counts,
    const float* __restrict__ Wsrc, const float* __restrict__ Wdst,
    const float* __restrict__ Wa1f,
    float* __restrict__ Wsa, float* __restrict__ Wda,
    const float* __restrict__ Wp2, const float* __restrict__ Wa2,
    unsigned short* __restrict__ W2B, unsigned short* __restrict__ Wa1B,
    unsigned short* __restrict__ Wa2B) {
  const int b = blockIdx.x;
  if (b < 3125) {                      // count
    const int e = b * 256 + threadIdx.x;
    if (e < NE) atomicAdd(&counts[ei[NE + e]], 1);
  } else if (b < 3125 + 64) {          // fold_w: Wsa = Wsrc@Wa1, Wda = Wdst@Wa1
    const int i = (b - 3125) * 256 + threadIdx.x;   // 16384 total
    const int m = i >> 13;
    const int kj = i & 8191;
    const int k = kj >> 6, j = kj & 63;
    const float* __restrict__ W = m ? Wdst : Wsrc;
    float acc = 0.f;
    #pragma unroll 4
    for (int q = 0; q < 128; ++q) acc = fmaf(W[k * 128 + q], Wa1f[q * 64 + j], acc);
    (m ? Wda : Wsa)[k * 64 + j] = acc;
  } else {                             // pack_w: B-frag order bf16
    const int t = (b - 3125 - 64) * 256 + threadIdx.x;  // 24576 total
    const int u = t & 8191;
    const int j = u & 7, l = (u >> 3) & 63;
    const int lk = (l >> 4) * 8 + j, ln = l & 15;
    if (t < 8192) {            // Wp2 [64][128]: 2 kb x 8 nb
      const int nb = (u >> 9) & 7, kb = u >> 12;
      W2B[u] = bf16rn(Wp2[(kb * 32 + lk) * 128 + nb * 16 + ln]);
    } else if (t < 16384) {    // Wa1 [128][64]: 4 kb x 4 nb
      const int nb = (u >> 9) & 3, kb = u >> 11;
      Wa1B[u] = bf16rn(Wa1f[(kb * 32 + lk) * 64 + nb * 16 + ln]);
    } else {                   // Wa2 [64][128]: 2 kb x 8 nb
      const int nb = (u >> 9) & 7, kb = u >> 12;
      Wa2B[u] = bf16rn(Wa2[(kb * 32 + lk) * 128 + nb * 16 + ln]);
    }
  }
}

__global__ __launch_bounds__(256) void scan_block(const int* __restrict__ counts,
                                                  int* __restrict__ ep,
                                                  int* __restrict__ blocksum) {
  const int i = blockIdx.x * 256 + threadIdx.x;
  const int lane = threadIdx.x & 63;
  const int w = threadIdx.x >> 6;
  const int v = (i < NN) ? counts[i] : 0;
  int s = v;
  #pragma unroll
  for (int off = 1; off < 64; off <<= 1) {
    const int t = __shfl_up(s, off, 64);
    if (lane >= off) s += t;
  }
  __shared__ int wsums[4];
  if (lane == 63) wsums[w] = s;
  __syncthreads();
  int add = 0;
  for (int j = 0; j < w; ++j) add += wsums[j];
  s += add;
  if (i < NN) ep[i] = s - v;
  if (threadIdx.x == 255) blocksum[blockIdx.x] = s;
}

__global__ void scan_tops(const int* __restrict__ blocksum,
                          int* __restrict__ blockoff, int n) {
  const int lane = threadIdx.x;
  int carry = 0;
  for (int base = 0; base < n; base += 64) {
    const int i = base + lane;
    const int v = (i < n) ? blocksum[i] : 0;
    int s = v;
    #pragma unroll
    for (int off = 1; off < 64; off <<= 1) {
      const int t = __shfl_up(s, off, 64);
      if (lane >= off) s += t;
    }
    s += carry;
    if (i < n) blockoff[i] = s - v;
    carry = __shfl(s, 63, 64);
  }
}

__global__ __launch_bounds__(256) void scan_finish(const int* __restrict__ ep,
                                                   const int* __restrict__ blockoff,
                                                   int* __restrict__ cursor,
                                                   int* __restrict__ rowptr) {
  const int i = blockIdx.x * 256 + threadIdx.x;
  if (i < NN) {
    const int v = ep[i] + blockoff[blockIdx.x];
    cursor[i] = v;
    rowptr[i] = v;
  }
  if (i == 0) rowptr[NN] = NE;
}

// ---------------- fused: scatter (3125 blocks) + node GEMMs (3125 blocks) ----------------
__global__ __launch_bounds__(256) void scatter_gemm3(
    const int* __restrict__ ei, int* __restrict__ cursor,
    int* __restrict__ ssrc, int* __restrict__ sdst,
    const float* __restrict__ x, const float* __restrict__ Wl,
    const float* __restrict__ Wsa, const float* __restrict__ Wda,
    float* __restrict__ h, float* __restrict__ as1, float* __restrict__ ad1) {
  if (blockIdx.x < 3125) {             // scatter
    const int e = blockIdx.x * 256 + threadIdx.x;
    if (e < NE) {
      const int s = ei[e], d = ei[NE + e];
      const int p = atomicAdd(&cursor[d], 1);
      ssrc[p] = s;
      sdst[p] = d;
    }
    return;
  }
  // gemm3
  const int wtask = __builtin_amdgcn_readfirstlane(
      (int)(((blockIdx.x - 3125) * 256 + threadIdx.x) >> 6));
  if (wtask >= 3125 * 4) return;
  const int lane = threadIdx.x & 63;
  const int rg = wtask >> 2;
  const int chunk = wtask & 3;
  const float* __restrict__ W = (chunk <= 1) ? Wl : ((chunk == 2) ? Wsa : Wda);
  float* __restrict__ O = (chunk <= 1) ? h : ((chunk == 2) ? as1 : ad1);
  const int ldw = (chunk <= 1) ? 128 : 64;
  const int col = ((chunk == 1) ? 64 : 0) + lane;
  const int r0 = rg * 16;
  float acc[16];
  #pragma unroll
  for (int r = 0; r < 16; ++r) acc[r] = 0.f;
  const float4* x4 = (const float4*)x;
  #pragma unroll 1
  for (int k4 = 0; k4 < 32; ++k4) {
    const float w0 = W[(size_t)(k4 * 4 + 0) * ldw + col];
    const float w1 = W[(size_t)(k4 * 4 + 1) * ldw + col];
    const float w2 = W[(size_t)(k4 * 4 + 2) * ldw + col];
    const float w3 = W[(size_t)(k4 * 4 + 3) * ldw + col];
    #pragma unroll
    for (int r = 0; r < 16; ++r) {
      const float4 xr = x4[(size_t)(r0 + r) * 32 + k4];
      acc[r] = fmaf(xr.x, w0, fmaf(xr.y, w1, fmaf(xr.z, w2, fmaf(xr.w, w3, acc[r]))));
    }
  }
  #pragma unroll
  for (int r = 0; r < 16; ++r) O[(size_t)(r0 + r) * ldw + col] = acc[r];
}

// ---------------- MFMA edge kernel (R16 + register diet -> 2 waves/SIMD) ----------------
// R16 freed ~88 VGPRs via LDS-staged weights (252->164). Close the remaining
// 36-reg gap to the 128-reg occupancy step:
//  1. gDiff precompute dropped: ad1/as1 loaded per-nb as GEMM2 C-init (-16)
//  2. meta/pos software pipeline dropped (-12): TLP replaces it at 2 waves/SIMD
//  3. __launch_bounds__(256,2) forces the <=128 budget
// Math identical to R16 (absmax invariant 0.015625).
__global__ __launch_bounds__(256, 2) void edge_mfma(
    const int* __restrict__ ssrc, const int* __restrict__ sdst,
    const int* __restrict__ rowptr, const float* __restrict__ pos,
    const float* __restrict__ hbuf, const float* __restrict__ as1, const float* __restrict__ ad1,
    const float* __restrict__ Wp1, const float* __restrict__ bp1,
    const unsigned short* __restrict__ W2B, const float* __restrict__ bp2,
    const unsigned short* __restrict__ Wa1B, const float* __restrict__ ba1,
    const unsigned short* __restrict__ Wa2B, const float* __restrict__ ba2,
    float* __restrict__ out, float* __restrict__ stag) {
  __shared__ uint4 ldsq[4][384];           // 6KB/wave: [0,4096) delta bf16, [4096,6144) ha bf16
  __shared__ unsigned short sW2B[8192], sWa1B[8192], sWa2B[8192];  // 48KB weights
  // stage weights: 3 x 1024 uint4 via 256 threads (4 each), one barrier
  {
    const uint4* g0 = (const uint4*)W2B;
    const uint4* g1 = (const uint4*)Wa1B;
    const uint4* g2 = (const uint4*)Wa2B;
    uint4* t0 = (uint4*)sW2B;
    uint4* t1 = (uint4*)sWa1B;
    uint4* t2 = (uint4*)sWa2B;
    #pragma unroll
    for (int k = 0; k < 4; ++k) {
      const int idx = k * 256 + threadIdx.x;
      t0[idx] = g0[idx];
      t1[idx] = g1[idx];
      t2[idx] = g2[idx];
    }
  }
  __syncthreads();

  const int wv = threadIdx.x >> 6;
  char* lbase = (char*)&ldsq[wv][0];
  const int lane = threadIdx.x & 63;
  const int g = lane >> 4;
  const int cl = lane & 15;
  const int wid = blockIdx.x * 4 + wv;
  const int wb = wid * 64;

  float cX[8], cY[8];
  #pragma unroll
  for (int nb = 0; nb < 8; ++nb) { cX[nb] = 0.f; cY[nb] = 0.f; }
  int carry_d = -1;

  #pragma unroll 1
  for (int st = 0; st < 4; ++st) {
    const int eb = wb + st * 16;
    const int myS = ssrc[eb + cl];
    const int myD = sdst[eb + cl];
    int dm[4], sm[4];
    #pragma unroll
    for (int i = 0; i < 4; ++i) {
      dm[i] = __shfl(myD, 4 * g + i, 64);
      sm[i] = __shfl(myS, 4 * g + i, 64);
    }
    const int f_d = __shfl(myD, 0, 64);
    const int l_d = __shfl(myD, 15, 64);

    const float2 pD = ((const float2*)pos)[myD];
    const float2 pS = ((const float2*)pos)[myS];
    const float p0 = pD.x - pS.x, p1 = pD.y - pS.y;
    s16x8 a1[2];
    #pragma unroll
    for (int kb = 0; kb < 2; ++kb) {
      const int k0 = kb * 32 + g * 8;
      const float4 wA = *(const float4*)(Wp1 + k0);
      const float4 wB = *(const float4*)(Wp1 + k0 + 4);
      const float4 vA = *(const float4*)(Wp1 + 64 + k0);
      const float4 vB = *(const float4*)(Wp1 + 64 + k0 + 4);
      const float4 bA = *(const float4*)(bp1 + k0);
      const float4 bB = *(const float4*)(bp1 + k0 + 4);
      float f0 = fmaxf(fmaf(p0, wA.x, fmaf(p1, vA.x, bA.x)), 0.f);
      float f1 = fmaxf(fmaf(p0, wA.y, fmaf(p1, vA.y, bA.y)), 0.f);
      float f2 = fmaxf(fmaf(p0, wA.z, fmaf(p1, vA.z, bA.z)), 0.f);
      float f3 = fmaxf(fmaf(p0, wA.w, fmaf(p1, vA.w, bA.w)), 0.f);
      float f4 = fmaxf(fmaf(p0, wB.x, fmaf(p1, vB.x, bB.x)), 0.f);
      float f5 = fmaxf(fmaf(p0, wB.y, fmaf(p1, vB.y, bB.y)), 0.f);
      float f6 = fmaxf(fmaf(p0, wB.z, fmaf(p1, vB.z, bB.z)), 0.f);
      float f7 = fmaxf(fmaf(p0, wB.w, fmaf(p1, vB.w, bB.w)), 0.f);
      uint4 q;
      q.x = packbf2(f0, f1); q.y = packbf2(f2, f3);
      q.z = packbf2(f4, f5); q.w = packbf2(f6, f7);
      a1[kb] = __builtin_bit_cast(s16x8, q);
    }

    // GEMM1: delta = hd@Wp2 + bp2, relu -> LDS bf16 (swizzled)
    #pragma unroll
    for (int nb = 0; nb < 8; ++nb) {
      const float bias = bp2[nb * 16 + cl];
      f32x4 acc = {bias, bias, bias, bias};
      const s16x8 b0 = *(const s16x8*)(sW2B + ((0 * 8 + nb) * 64 + lane) * 8);
      const s16x8 b1 = *(const s16x8*)(sW2B + ((1 * 8 + nb) * 64 + lane) * 8);
      acc = __builtin_amdgcn_mfma_f32_16x16x32_bf16(a1[0], b0, acc, 0, 0, 0);
      acc = __builtin_amdgcn_mfma_f32_16x16x32_bf16(a1[1], b1, acc, 0, 0, 0);
      #pragma unroll
      for (int i = 0; i < 4; ++i) {
        const int row = g * 4 + i;
        const int byt = (row << 8) + ((((nb * 16 + cl) * 2)) ^ ((row & 7) << 5));
        *(unsigned short*)(lbase + byt) = bf16rn(fmaxf(acc[i], 0.f));
      }
    }

    s16x8 a2[4];
    #pragma unroll
    for (int kb = 0; kb < 4; ++kb) {
      const int byt = (cl << 8) + ((kb * 64 + g * 16) ^ ((cl & 7) << 5));
      a2[kb] = __builtin_bit_cast(s16x8, *(const uint4*)(lbase + byt));
    }

    // GEMM2: ha = relu((ad1[dst]-as1[src]) + relu(delta)@Wa1 + ba1) -> LDS
    #pragma unroll
    for (int nb = 0; nb < 4; ++nb) {
      const float b1v = ba1[nb * 16 + cl];
      f32x4 acc;
      #pragma unroll
      for (int i = 0; i < 4; ++i) {
        acc[i] = ad1[(size_t)dm[i] * 64 + nb * 16 + cl]
               - as1[(size_t)sm[i] * 64 + nb * 16 + cl] + b1v;
      }
      #pragma unroll
      for (int kb = 0; kb < 4; ++kb) {
        const s16x8 b = *(const s16x8*)(sWa1B + ((kb * 4 + nb) * 64 + lane) * 8);
        acc = __builtin_amdgcn_mfma_f32_16x16x32_bf16(a2[kb], b, acc, 0, 0, 0);
      }
      #pragma unroll
      for (int i = 0; i < 4; ++i) {
        const int row = g * 4 + i;
        const int byt = 4096 + (row << 7) + ((((nb * 16 + cl) * 2)) ^ ((row & 7) << 4));
        *(unsigned short*)(lbase + byt) = bf16rn(fmaxf(acc[i], 0.f));
      }
    }
    s16x8 a3[2];
    #pragma unroll
    for (int kb = 0; kb < 2; ++kb) {
      const int byt = 4096 + (cl << 7) + ((kb * 64 + g * 16) ^ ((cl & 7) << 4));
      a3[kb] = __builtin_bit_cast(s16x8, *(const uint4*)(lbase + byt));
    }

    // segment flags (sorted dst)
    const bool eq01 = dm[0] == dm[1], eq12 = dm[1] == dm[2], eq23 = dm[2] == dm[3];
    bool r_[4];
    r_[3] = true; r_[2] = eq23; r_[1] = eq12 && eq23; r_[0] = eq01 && eq12 && eq23;
    const int dnx = __shfl(myD, (4 * g + 4) & 15, 64);
    const bool cont = (g < 3) && (dm[3] == dnx);
    const float fullf = r_[0] ? 1.f : 0.f;
    const float fulln = __shfl_down(fullf, 16, 64);
    const int dpv = __shfl(myD, (4 * g - 1) & 15, 64);
    bool head[4];
    head[0] = (g == 0) ? true : (dm[0] != dpv);
    head[1] = dm[1] != dm[0];
    head[2] = dm[2] != dm[1];
    head[3] = dm[3] != dm[2];
    bool fin[4];
    #pragma unroll
    for (int i = 0; i < 4; ++i)
      fin[i] = head[i] && !(g == 0 && i == 0) && (dm[i] != l_d);

    const bool mismatch = (st != 0) && (carry_d != f_d);
    const bool seed = (st == 0) || mismatch;
    const bool closeFirst = (f_d != l_d);
    const int oldd = carry_d;
    int fo_final = 0, fo_slot = 0;
    if (mismatch) {
      const int q0 = rowptr[oldd], q1 = rowptr[oldd + 1];
      if (q0 >= wb && q1 <= wb + 64) fo_final = 1;
      else fo_slot = 2 * wid + ((q0 < wb) ? 0 : 1);
    }
    int fc_final = 0, fc_slot = 0;
    if (closeFirst) {
      const int q0 = rowptr[f_d], q1 = rowptr[f_d + 1];
      if (q0 >= wb && q1 <= wb + 64) fc_final = 1;
      else fc_slot = 2 * wid + ((q0 < wb) ? 0 : 1);
    }
    const unsigned long long bal = __ballot(myD == l_d);
    const int m_h = (int)__builtin_ctzll(bal & 0xffffull);
    const int i_h = m_h & 3, g_h = m_h >> 2;

    // merged GEMM3 + epilogue per nb (fully unrolled: static cX/cY index)
    float hgn[4];
    #pragma unroll
    for (int i = 0; i < 4; ++i) hgn[i] = hbuf[(size_t)sm[i] * 128 + cl];  // nb=0
    #pragma unroll
    for (int nb = 0; nb < 8; ++nb) {
      float del[4];
      #pragma unroll
      for (int i = 0; i < 4; ++i) {
        const int row = g * 4 + i;
        const int byt = (row << 8) + ((((nb * 16 + cl) * 2)) ^ ((row & 7) << 5));
        const unsigned short uu = *(const unsigned short*)(lbase + byt);
        del[i] = __builtin_bit_cast(float, ((unsigned)uu) << 16);
      }
      float hgc[4];
      #pragma unroll
      for (int i = 0; i < 4; ++i) hgc[i] = hgn[i];
      if (nb < 7) {
        #pragma unroll
        for (int i = 0; i < 4; ++i)
          hgn[i] = hbuf[(size_t)sm[i] * 128 + (nb + 1) * 16 + cl];  // rolling prefetch
      }
      const float b2v = ba2[nb * 16 + cl];
      f32x4 acc3 = {b2v, b2v, b2v, b2v};
      {
        const s16x8 b0 = *(const s16x8*)(sWa2B + ((0 * 8 + nb) * 64 + lane) * 8);
        const s16x8 b1 = *(const s16x8*)(sWa2B + ((1 * 8 + nb) * 64 + lane) * 8);
        acc3 = __builtin_amdgcn_mfma_f32_16x16x32_bf16(a3[0], b0, acc3, 0, 0, 0);
        acc3 = __builtin_amdgcn_mfma_f32_16x16x32_bf16(a3[1], b1, acc3, 0, 0, 0);
      }
      float x[4], y[4];
      #pragma unroll
      for (int i = 0; i < 4; ++i) {
        const float ee = __expf(fmaxf(acc3[i], 0.f));
        y[i] = ee;
        x[i] = ee * (hgc[i] + del[i]);
      }
      const float sx3 = x[3],                      sy3 = y[3];
      const float sx2 = x[2] + (eq23 ? sx3 : 0.f), sy2 = y[2] + (eq23 ? sy3 : 0.f);
      const float sx1 = x[1] + (eq12 ? sx2 : 0.f), sy1 = y[1] + (eq12 ? sy2 : 0.f);
      const float sx0 = x[0] + (eq01 ? sx1 : 0.f), sy0 = y[0] + (eq01 ? sy1 : 0.f);
      float Bx = 0.f, By = 0.f;
      #pragma unroll
      for (int tt = 0; tt < 3; ++tt) {
        const float nsx = __shfl_down(sx0, 16, 64);
        const float nsy = __shfl_down(sy0, 16, 64);
        const float nBx = __shfl_down(Bx, 16, 64);
        const float nBy = __shfl_down(By, 16, 64);
        Bx = cont ? (nsx + (fulln > 0.5f ? nBx : 0.f)) : 0.f;
        By = cont ? (nsy + (fulln > 0.5f ? nBy : 0.f)) : 0.f;
      }
      float hx[4], hy[4];
      #pragma unroll
      for (int i = 0; i < 4; ++i) {
        hx[i] = ((i == 0) ? sx0 : (i == 1) ? sx1 : (i == 2) ? sx2 : sx3) + (r_[i] ? Bx : 0.f);
        hy[i] = ((i == 0) ? sy0 : (i == 1) ? sy1 : (i == 2) ? sy2 : sy3) + (r_[i] ? By : 0.f);
      }
      const float h0x = __shfl(hx[0], cl, 64);
      const float h0y = __shfl(hy[0], cl, 64);
      if (mismatch && g == 0) {
        if (fo_final) {
          out[(size_t)oldd * 128 + nb * 16 + cl] = fmaxf(cX[nb] / (cY[nb] + 1e-16f), 0.f);
        } else {
          stag[(size_t)fo_slot * 256 + nb * 16 + cl] = cY[nb];
          stag[(size_t)fo_slot * 256 + 128 + nb * 16 + cl] = cX[nb];
        }
      }
      if (seed) { cX[nb] = h0x; cY[nb] = h0y; }
      else      { cX[nb] += h0x; cY[nb] += h0y; }
      if (closeFirst) {
        if (g == 0) {
          if (fc_final) {
            out[(size_t)f_d * 128 + nb * 16 + cl] = fmaxf(cX[nb] / (cY[nb] + 1e-16f), 0.f);
          } else {
            stag[(size_t)fc_slot * 256 + nb * 16 + cl] = cY[nb];
            stag[(size_t)fc_slot * 256 + 128 + nb * 16 + cl] = cX[nb];
          }
        }
        #pragma unroll
        for (int i = 0; i < 4; ++i)
          if (fin[i])
            out[(size_t)dm[i] * 128 + nb * 16 + cl] = fmaxf(hx[i] / (hy[i] + 1e-16f), 0.f);
        const float selx = (i_h == 0) ? hx[0] : (i_h == 1) ? hx[1] : (i_h == 2) ? hx[2] : hx[3];
        const float sely = (i_h == 0) ? hy[0] : (i_h == 1) ? hy[1] : (i_h == 2) ? hy[2] : hy[3];
        cX[nb] = __shfl(selx, g_h * 16 + cl, 64);
        cY[nb] = __shfl(sely, g_h * 16 + cl, 64);
      }
    }
    carry_d = l_d;
  }

  // wave-end flush
  {
    const int q0 = rowptr[carry_d], q1 = rowptr[carry_d + 1];
    const bool ffin = (q0 >= wb) && (q1 <= wb + 64);
    const int fslot = 2 * wid + ((q0 < wb) ? 0 : 1);
    if (g == 0) {
      #pragma unroll
      for (int nb = 0; nb < 8; ++nb) {
        if (ffin) {
          out[(size_t)carry_d * 128 + nb * 16 + cl] = fmaxf(cX[nb] / (cY[nb] + 1e-16f), 0.f);
        } else {
          stag[(size_t)fslot * 256 + nb * 16 + cl] = cY[nb];
          stag[(size_t)fslot * 256 + 128 + nb * 16 + cl] = cX[nb];
        }
      }
    }
  }
}

// ---------------- finalize: empty rows -> 0; spanning dsts -> sum staging ----------------
__global__ __launch_bounds__(256) void finalize_kernel(const int* __restrict__ rowptr,
                                                       const float* __restrict__ stag,
                                                       float* __restrict__ out) {
  const int idx = blockIdx.x * 256 + threadIdx.x;  // NN*32 threads
  const int d = idx >> 5;
  const int c4 = idx & 31;
  if (d >= NN) return;
  const int r0 = rowptr[d];
  const int r1 = rowptr[d + 1];
  float4* o4 = (float4*)(out + (size_t)d * 128 + c4 * 4);
  if (r0 == r1) {
    const float4 z = {0.f, 0.f, 0.f, 0.f};
    *o4 = z;
    return;
  }
  const int w0 = r0 >> 6;
  const int w1 = (r1 - 1) >> 6;
  if (w0 == w1) return;           // complete-in-wave: written by edge_mfma
  float ee0 = 0.f, ee1 = 0.f, ee2 = 0.f, ee3 = 0.f;
  float vv0 = 0.f, vv1 = 0.f, vv2 = 0.f, vv3 = 0.f;
  int slot = 2 * w0 + 1;
  for (int w = w0; w <= w1; ++w) {
    const float* sp = stag + (size_t)slot * 256;
    const float4 a = *(const float4*)(sp + c4 * 4);
    const float4 b = *(const float4*)(sp + 128 + c4 * 4);
    ee0 += a.x; ee1 += a.y; ee2 += a.z; ee3 += a.w;
    vv0 += b.x; vv1 += b.y; vv2 += b.z; vv3 += b.w;
    slot = 2 * (w + 1);
  }
  float4 r;
  r.x = fmaxf(vv0 / (ee0 + 1e-16f), 0.f);
  r.y = fmaxf(vv1 / (ee1 + 1e-16f), 0.f);
  r.z = fmaxf(vv2 / (ee2 + 1e-16f), 0.f);
  r.w = fmaxf(vv3 / (ee3 + 1e-16f), 0.f);
  *o4 = r;
}

extern "C" void kernel_launch(void* const* d_in, const int* in_sizes, int n_in,
                              void* d_out, int out_size, void* d_ws, size_t ws_size,
                              hipStream_t stream) {
  const float* x     = (const float*)d_in[0];
  const float* pos   = (const float*)d_in[1];
  const int*   ei    = (const int*)d_in[2];
  const float* W_lin = (const float*)d_in[3];
  const float* W_src = (const float*)d_in[4];
  const float* W_dst = (const float*)d_in[5];
  const float* Wp1   = (const float*)d_in[6];
  const float* bp1   = (const float*)d_in[7];
  const float* Wp2   = (const float*)d_in[8];
  const float* bp2   = (const float*)d_in[9];
  const float* Wa1   = (const float*)d_in[10];
  const float* ba1   = (const float*)d_in[11];
  const float* Wa2   = (const float*)d_in[12];
  const float* ba2   = (const float*)d_in[13];
  float* out = (float*)d_out;

  // workspace layout (~92 MB)
  float* h    = (float*)d_ws;                        // NN*128
  float* as1  = h   + (size_t)NN * 128;              // NN*64
  float* ad1  = as1 + (size_t)NN * 64;               // NN*64
  float* stag = ad1 + (size_t)NN * 64;               // 25000*256
  float* Wsa  = stag + (size_t)25000 * 256;          // 128*64
  float* Wda  = Wsa + 128 * 64;                      // 128*64
  unsigned short* W2B  = (unsigned short*)(Wda + 128 * 64);  // 8192
  unsigned short* Wa1B = W2B + 8192;                 // 8192
  unsigned short* Wa2B = Wa1B + 8192;                // 8192
  int* counts   = (int*)(Wa2B + 8192);               // NN
  int* ep       = counts + NN;
  int* cursor   = ep + NN;
  int* rowptr   = cursor + NN;                       // NN+1
  int* blocksum = rowptr + NN + 1;
  int* blockoff = blocksum + 196;
  int* ssrc     = blockoff + 196;                    // NE
  int* sdst     = ssrc + NE;                         // NE

  zero_counts<<<196, 256, 0, stream>>>(counts);
  count_fold_pack<<<3285, 256, 0, stream>>>(ei, counts, W_src, W_dst, Wa1,
                                            Wsa, Wda, Wp2, Wa2, W2B, Wa1B, Wa2B);
  scan_block<<<196, 256, 0, stream>>>(counts, ep, blocksum);
  scan_tops<<<1, 64, 0, stream>>>(blocksum, blockoff, 196);
  scan_finish<<<196, 256, 0, stream>>>(ep, blockoff, cursor, rowptr);
  scatter_gemm3<<<6250, 256, 0, stream>>>(ei, cursor, ssrc, sdst,
                                          x, W_lin, Wsa, Wda, h, as1, ad1);
  edge_mfma<<<3125, 256, 0, stream>>>(ssrc, sdst, rowptr, pos, h, as1, ad1,
                                      Wp1, bp1, W2B, bp2, Wa1B, ba1, Wa2B, ba2,
                                      out, stag);
  finalize_kernel<<<6250, 256, 0, stream>>>(rowptr, stag, out);
}

// Round 18
// 559.573 us; speedup vs baseline: 1.0667x; 1.0667x over previous
//
#include <hip/hip_runtime.h>
#include <hip/hip_bf16.h>

#define NN 50000
#define NE 800000

typedef short s16x8 __attribute__((ext_vector_type(8)));
typedef float f32x4 __attribute__((ext_vector_type(4)));

__device__ __forceinline__ unsigned packbf2(float a, float b) {
  __hip_bfloat162 h = __float22bfloat162_rn(make_float2(a, b));
  return *reinterpret_cast<unsigned*>(&h);
}
__device__ __forceinline__ unsigned short bf16rn(float x) {
  return (unsigned short)(packbf2(x, x) & 0xffffu);
}

// ---------------- zero counts ----------------
__global__ __launch_bounds__(256) void zero_counts(int* __restrict__ counts) {
  const int i = blockIdx.x * 256 + threadIdx.x;
  if (i < NN) counts[i] = 0;
}

// ---------------- fused: CSR count (3125 blocks) + fold_w (64) + pack_w (96) ----------------
__global__ __launch_bounds__(256) void count_fold_pack(
    const int* __restrict__ ei, int* __restrict__ counts,
    const float* __restrict__ Wsrc, const float* __restrict__ Wdst,
    const float* __restrict__ Wa1f,
    float* __restrict__ Wsa, float* __restrict__ Wda,
    const float* __restrict__ Wp2, const float* __restrict__ Wa2,
    unsigned short* __restrict__ W2B, unsigned short* __restrict__ Wa1B,
    unsigned short* __restrict__ Wa2B) {
  const int b = blockIdx.x;
  if (b < 3125) {                      // count
    const int e = b * 256 + threadIdx.x;
    if (e < NE) atomicAdd(&counts[ei[NE + e]], 1);
  } else if (b < 3125 + 64) {          // fold_w: Wsa = Wsrc@Wa1, Wda = Wdst@Wa1
    const int i = (b - 3125) * 256 + threadIdx.x;   // 16384 total
    const int m = i >> 13;
    const int kj = i & 8191;
    const int k = kj >> 6, j = kj & 63;
    const float* __restrict__ W = m ? Wdst : Wsrc;
    float acc = 0.f;
    #pragma unroll 4
    for (int q = 0; q < 128; ++q) acc = fmaf(W[k * 128 + q], Wa1f[q * 64 + j], acc);
    (m ? Wda : Wsa)[k * 64 + j] = acc;
  } else {                             // pack_w: B-frag order bf16
    const int t = (b - 3125 - 64) * 256 + threadIdx.x;  // 24576 total
    const int u = t & 8191;
    const int j = u & 7, l = (u >> 3) & 63;
    const int lk = (l >> 4) * 8 + j, ln = l & 15;
    if (t < 8192) {            // Wp2 [64][128]: 2 kb x 8 nb
      const int nb = (u >> 9) & 7, kb = u >> 12;
      W2B[u] = bf16rn(Wp2[(kb * 32 + lk) * 128 + nb * 16 + ln]);
    } else if (t < 16384) {    // Wa1 [128][64]: 4 kb x 4 nb
      const int nb = (u >> 9) & 3, kb = u >> 11;
      Wa1B[u] = bf16rn(Wa1f[(kb * 32 + lk) * 64 + nb * 16 + ln]);
    } else {                   // Wa2 [64][128]: 2 kb x 8 nb
      const int nb = (u >> 9) & 7, kb = u >> 12;
      Wa2B[u] = bf16rn(Wa2[(kb * 32 + lk) * 128 + nb * 16 + ln]);
    }
  }
}

__global__ __launch_bounds__(256) void scan_block(const int* __restrict__ counts,
                                                  int* __restrict__ ep,
                                                  int* __restrict__ blocksum) {
  const int i = blockIdx.x * 256 + threadIdx.x;
  const int lane = threadIdx.x & 63;
  const int w = threadIdx.x >> 6;
  const int v = (i < NN) ? counts[i] : 0;
  int s = v;
  #pragma unroll
  for (int off = 1; off < 64; off <<= 1) {
    const int t = __shfl_up(s, off, 64);
    if (lane >= off) s += t;
  }
  __shared__ int wsums[4];
  if (lane == 63) wsums[w] = s;
  __syncthreads();
  int add = 0;
  for (int j = 0; j < w; ++j) add += wsums[j];
  s += add;
  if (i < NN) ep[i] = s - v;
  if (threadIdx.x == 255) blocksum[blockIdx.x] = s;
}

__global__ void scan_tops(const int* __restrict__ blocksum,
                          int* __restrict__ blockoff, int n) {
  const int lane = threadIdx.x;
  int carry = 0;
  for (int base = 0; base < n; base += 64) {
    const int i = base + lane;
    const int v = (i < n) ? blocksum[i] : 0;
    int s = v;
    #pragma unroll
    for (int off = 1; off < 64; off <<= 1) {
      const int t = __shfl_up(s, off, 64);
      if (lane >= off) s += t;
    }
    s += carry;
    if (i < n) blockoff[i] = s - v;
    carry = __shfl(s, 63, 64);
  }
}

__global__ __launch_bounds__(256) void scan_finish(const int* __restrict__ ep,
                                                   const int* __restrict__ blockoff,
                                                   int* __restrict__ cursor,
                                                   int* __restrict__ rowptr) {
  const int i = blockIdx.x * 256 + threadIdx.x;
  if (i < NN) {
    const int v = ep[i] + blockoff[blockIdx.x];
    cursor[i] = v;
    rowptr[i] = v;
  }
  if (i == 0) rowptr[NN] = NE;
}

// ---------------- fused: scatter (3125 blocks) + node GEMMs (3125 blocks) ----------------
__global__ __launch_bounds__(256) void scatter_gemm3(
    const int* __restrict__ ei, int* __restrict__ cursor,
    int* __restrict__ ssrc, int* __restrict__ sdst,
    const float* __restrict__ x, const float* __restrict__ Wl,
    const float* __restrict__ Wsa, const float* __restrict__ Wda,
    float* __restrict__ h, float* __restrict__ as1, float* __restrict__ ad1) {
  if (blockIdx.x < 3125) {             // scatter
    const int e = blockIdx.x * 256 + threadIdx.x;
    if (e < NE) {
      const int s = ei[e], d = ei[NE + e];
      const int p = atomicAdd(&cursor[d], 1);
      ssrc[p] = s;
      sdst[p] = d;
    }
    return;
  }
  // gemm3
  const int wtask = __builtin_amdgcn_readfirstlane(
      (int)(((blockIdx.x - 3125) * 256 + threadIdx.x) >> 6));
  if (wtask >= 3125 * 4) return;
  const int lane = threadIdx.x & 63;
  const int rg = wtask >> 2;
  const int chunk = wtask & 3;
  const float* __restrict__ W = (chunk <= 1) ? Wl : ((chunk == 2) ? Wsa : Wda);
  float* __restrict__ O = (chunk <= 1) ? h : ((chunk == 2) ? as1 : ad1);
  const int ldw = (chunk <= 1) ? 128 : 64;
  const int col = ((chunk == 1) ? 64 : 0) + lane;
  const int r0 = rg * 16;
  float acc[16];
  #pragma unroll
  for (int r = 0; r < 16; ++r) acc[r] = 0.f;
  const float4* x4 = (const float4*)x;
  #pragma unroll 1
  for (int k4 = 0; k4 < 32; ++k4) {
    const float w0 = W[(size_t)(k4 * 4 + 0) * ldw + col];
    const float w1 = W[(size_t)(k4 * 4 + 1) * ldw + col];
    const float w2 = W[(size_t)(k4 * 4 + 2) * ldw + col];
    const float w3 = W[(size_t)(k4 * 4 + 3) * ldw + col];
    #pragma unroll
    for (int r = 0; r < 16; ++r) {
      const float4 xr = x4[(size_t)(r0 + r) * 32 + k4];
      acc[r] = fmaf(xr.x, w0, fmaf(xr.y, w1, fmaf(xr.z, w2, fmaf(xr.w, w3, acc[r]))));
    }
  }
  #pragma unroll
  for (int r = 0; r < 16; ++r) O[(size_t)(r0 + r) * ldw + col] = acc[r];
}

// ---------------- MFMA edge kernel (pairwise-ILP + LDS-staged weights) ----------------
// R12's pair structure (2x memory-level parallelism on gather/GEMM chains)
// finally fits the 256-reg cap because R16's LDS weight staging freed ~88
// regs of weight addressing (330-88 ~= 242). Wave = 64 edges = 2 pairs of
// 16-edge subtiles; per pair both subtiles' gathers/GEMM1/GEMM2 issue
// back-to-back into separate 6KB LDS regions; epilogues sequential (carry).
// LDS: 48KB pair-regions + 48KB weights = 96KB/block.
__global__ __launch_bounds__(256) void edge_mfma(
    const int* __restrict__ ssrc, const int* __restrict__ sdst,
    const int* __restrict__ rowptr, const float* __restrict__ pos,
    const float* __restrict__ hbuf, const float* __restrict__ as1, const float* __restrict__ ad1,
    const float* __restrict__ Wp1, const float* __restrict__ bp1,
    const unsigned short* __restrict__ W2B, const float* __restrict__ bp2,
    const unsigned short* __restrict__ Wa1B, const float* __restrict__ ba1,
    const unsigned short* __restrict__ Wa2B, const float* __restrict__ ba2,
    float* __restrict__ out, float* __restrict__ stag) {
  __shared__ uint4 ldsq[4][768];   // 12KB/wave: region q at q*6144: [0,4096) delta, [4096,6144) ha
  __shared__ unsigned short sW2B[8192], sWa1B[8192], sWa2B[8192];  // 48KB weights
  {
    const uint4* g0 = (const uint4*)W2B;
    const uint4* g1 = (const uint4*)Wa1B;
    const uint4* g2 = (const uint4*)Wa2B;
    uint4* t0 = (uint4*)sW2B;
    uint4* t1 = (uint4*)sWa1B;
    uint4* t2 = (uint4*)sWa2B;
    #pragma unroll
    for (int k = 0; k < 4; ++k) {
      const int idx = k * 256 + threadIdx.x;
      t0[idx] = g0[idx];
      t1[idx] = g1[idx];
      t2[idx] = g2[idx];
    }
  }
  __syncthreads();

  const int wv = threadIdx.x >> 6;
  char* lb0 = (char*)&ldsq[wv][0];
  const int lane = threadIdx.x & 63;
  const int g = lane >> 4;
  const int cl = lane & 15;
  const int wid = blockIdx.x * 4 + wv;
  const int wb = wid * 64;

  float cX[8], cY[8];
  #pragma unroll
  for (int nb = 0; nb < 8; ++nb) { cX[nb] = 0.f; cY[nb] = 0.f; }
  int carry_d = -1;

  #pragma unroll 1
  for (int p = 0; p < 2; ++p) {
    // ---- meta both subtiles ----
    int myS[2], myD[2];
    myS[0] = ssrc[wb + p * 32 + cl];      myD[0] = sdst[wb + p * 32 + cl];
    myS[1] = ssrc[wb + p * 32 + 16 + cl]; myD[1] = sdst[wb + p * 32 + 16 + cl];
    int dm[2][4], sm[2][4], f_d[2], l_d[2];
    #pragma unroll
    for (int q = 0; q < 2; ++q) {
      #pragma unroll
      for (int i = 0; i < 4; ++i) {
        dm[q][i] = __shfl(myD[q], 4 * g + i, 64);
        sm[q][i] = __shfl(myS[q], 4 * g + i, 64);
      }
      f_d[q] = __shfl(myD[q], 0, 64);
      l_d[q] = __shfl(myD[q], 15, 64);
    }

    // ---- gDiff both subtiles: 16 loads in flight ----
    float gDiff[2][4][4];
    #pragma unroll
    for (int q = 0; q < 2; ++q) {
      #pragma unroll
      for (int i = 0; i < 4; ++i) {
        #pragma unroll
        for (int nb = 0; nb < 4; ++nb) {
          gDiff[q][i][nb] = ad1[(size_t)dm[q][i] * 64 + nb * 16 + cl]
                          - as1[(size_t)sm[q][i] * 64 + nb * 16 + cl];
        }
      }
    }

    // ---- hd -> A1 frags, both subtiles ----
    s16x8 a1[2][2];
    #pragma unroll
    for (int q = 0; q < 2; ++q) {
      const float2 pD = ((const float2*)pos)[myD[q]];
      const float2 pS = ((const float2*)pos)[myS[q]];
      const float p0 = pD.x - pS.x, p1 = pD.y - pS.y;
      #pragma unroll
      for (int kb = 0; kb < 2; ++kb) {
        const int k0 = kb * 32 + g * 8;
        const float4 wA = *(const float4*)(Wp1 + k0);
        const float4 wB = *(const float4*)(Wp1 + k0 + 4);
        const float4 vA = *(const float4*)(Wp1 + 64 + k0);
        const float4 vB = *(const float4*)(Wp1 + 64 + k0 + 4);
        const float4 bA = *(const float4*)(bp1 + k0);
        const float4 bB = *(const float4*)(bp1 + k0 + 4);
        float f0 = fmaxf(fmaf(p0, wA.x, fmaf(p1, vA.x, bA.x)), 0.f);
        float f1 = fmaxf(fmaf(p0, wA.y, fmaf(p1, vA.y, bA.y)), 0.f);
        float f2 = fmaxf(fmaf(p0, wA.z, fmaf(p1, vA.z, bA.z)), 0.f);
        float f3 = fmaxf(fmaf(p0, wA.w, fmaf(p1, vA.w, bA.w)), 0.f);
        float f4 = fmaxf(fmaf(p0, wB.x, fmaf(p1, vB.x, bB.x)), 0.f);
        float f5 = fmaxf(fmaf(p0, wB.y, fmaf(p1, vB.y, bB.y)), 0.f);
        float f6 = fmaxf(fmaf(p0, wB.z, fmaf(p1, vB.z, bB.z)), 0.f);
        float f7 = fmaxf(fmaf(p0, wB.w, fmaf(p1, vB.w, bB.w)), 0.f);
        uint4 qq;
        qq.x = packbf2(f0, f1); qq.y = packbf2(f2, f3);
        qq.z = packbf2(f4, f5); qq.w = packbf2(f6, f7);
        a1[q][kb] = __builtin_bit_cast(s16x8, qq);
      }
    }

    // ---- GEMM1 both subtiles -> own LDS delta regions ----
    #pragma unroll
    for (int q = 0; q < 2; ++q) {
      char* lbq = lb0 + q * 6144;
      #pragma unroll
      for (int nb = 0; nb < 8; ++nb) {
        const float bias = bp2[nb * 16 + cl];
        f32x4 acc = {bias, bias, bias, bias};
        const s16x8 b0 = *(const s16x8*)(sW2B + ((0 * 8 + nb) * 64 + lane) * 8);
        const s16x8 b1 = *(const s16x8*)(sW2B + ((1 * 8 + nb) * 64 + lane) * 8);
        acc = __builtin_amdgcn_mfma_f32_16x16x32_bf16(a1[q][0], b0, acc, 0, 0, 0);
        acc = __builtin_amdgcn_mfma_f32_16x16x32_bf16(a1[q][1], b1, acc, 0, 0, 0);
        #pragma unroll
        for (int i = 0; i < 4; ++i) {
          const int row = g * 4 + i;
          const int byt = (row << 8) + ((((nb * 16 + cl) * 2)) ^ ((row & 7) << 5));
          *(unsigned short*)(lbq + byt) = bf16rn(fmaxf(acc[i], 0.f));
        }
      }
    }

    // ---- A2 + GEMM2 both subtiles -> own LDS ha regions ----
    #pragma unroll
    for (int q = 0; q < 2; ++q) {
      char* lbq = lb0 + q * 6144;
      s16x8 a2[4];
      #pragma unroll
      for (int kb = 0; kb < 4; ++kb) {
        const int byt = (cl << 8) + ((kb * 64 + g * 16) ^ ((cl & 7) << 5));
        a2[kb] = __builtin_bit_cast(s16x8, *(const uint4*)(lbq + byt));
      }
      #pragma unroll
      for (int nb = 0; nb < 4; ++nb) {
        const float b1v = ba1[nb * 16 + cl];
        f32x4 acc = {gDiff[q][0][nb] + b1v, gDiff[q][1][nb] + b1v,
                     gDiff[q][2][nb] + b1v, gDiff[q][3][nb] + b1v};
        #pragma unroll
        for (int kb = 0; kb < 4; ++kb) {
          const s16x8 b = *(const s16x8*)(sWa1B + ((kb * 4 + nb) * 64 + lane) * 8);
          acc = __builtin_amdgcn_mfma_f32_16x16x32_bf16(a2[kb], b, acc, 0, 0, 0);
        }
        #pragma unroll
        for (int i = 0; i < 4; ++i) {
          const int row = g * 4 + i;
          const int byt = 4096 + (row << 7) + ((((nb * 16 + cl) * 2)) ^ ((row & 7) << 4));
          *(unsigned short*)(lbq + byt) = bf16rn(fmaxf(acc[i], 0.f));
        }
      }
    }

    // ---- per-subtile GEMM3 + epilogue (sequential: carry chain) ----
    #pragma unroll
    for (int q = 0; q < 2; ++q) {
      char* lbq = lb0 + q * 6144;
      s16x8 a3[2];
      #pragma unroll
      for (int kb = 0; kb < 2; ++kb) {
        const int byt = 4096 + (cl << 7) + ((kb * 64 + g * 16) ^ ((cl & 7) << 4));
        a3[kb] = __builtin_bit_cast(s16x8, *(const uint4*)(lbq + byt));
      }

      const bool eq01 = dm[q][0] == dm[q][1], eq12 = dm[q][1] == dm[q][2],
                 eq23 = dm[q][2] == dm[q][3];
      bool r_[4];
      r_[3] = true; r_[2] = eq23; r_[1] = eq12 && eq23; r_[0] = eq01 && eq12 && eq23;
      const int dnx = __shfl(myD[q], (4 * g + 4) & 15, 64);
      const bool cont = (g < 3) && (dm[q][3] == dnx);
      const float fullf = r_[0] ? 1.f : 0.f;
      const float fulln = __shfl_down(fullf, 16, 64);
      const int dpv = __shfl(myD[q], (4 * g - 1) & 15, 64);
      bool head[4];
      head[0] = (g == 0) ? true : (dm[q][0] != dpv);
      head[1] = dm[q][1] != dm[q][0];
      head[2] = dm[q][2] != dm[q][1];
      head[3] = dm[q][3] != dm[q][2];
      bool fin[4];
      #pragma unroll
      for (int i = 0; i < 4; ++i)
        fin[i] = head[i] && !(g == 0 && i == 0) && (dm[q][i] != l_d[q]);

      const int st = p * 2 + q;
      const bool mismatch = (st != 0) && (carry_d != f_d[q]);
      const bool seed = (st == 0) || mismatch;
      const bool closeFirst = (f_d[q] != l_d[q]);
      const int oldd = carry_d;
      int fo_final = 0, fo_slot = 0;
      if (mismatch) {
        const int q0 = rowptr[oldd], q1 = rowptr[oldd + 1];
        if (q0 >= wb && q1 <= wb + 64) fo_final = 1;
        else fo_slot = 2 * wid + ((q0 < wb) ? 0 : 1);
      }
      int fc_final = 0, fc_slot = 0;
      if (closeFirst) {
        const int q0 = rowptr[f_d[q]], q1 = rowptr[f_d[q] + 1];
        if (q0 >= wb && q1 <= wb + 64) fc_final = 1;
        else fc_slot = 2 * wid + ((q0 < wb) ? 0 : 1);
      }
      const unsigned long long bal = __ballot(myD[q] == l_d[q]);
      const int m_h = (int)__builtin_ctzll(bal & 0xffffull);
      const int i_h = m_h & 3, g_h = m_h >> 2;

      float hgn[4];
      #pragma unroll
      for (int i = 0; i < 4; ++i) hgn[i] = hbuf[(size_t)sm[q][i] * 128 + cl];  // nb=0
      #pragma unroll
      for (int nb = 0; nb < 8; ++nb) {
        float del[4];
        #pragma unroll
        for (int i = 0; i < 4; ++i) {
          const int row = g * 4 + i;
          const int byt = (row << 8) + ((((nb * 16 + cl) * 2)) ^ ((row & 7) << 5));
          const unsigned short uu = *(const unsigned short*)(lbq + byt);
          del[i] = __builtin_bit_cast(float, ((unsigned)uu) << 16);
        }
        float hgc[4];
        #pragma unroll
        for (int i = 0; i < 4; ++i) hgc[i] = hgn[i];
        if (nb < 7) {
          #pragma unroll
          for (int i = 0; i < 4; ++i)
            hgn[i] = hbuf[(size_t)sm[q][i] * 128 + (nb + 1) * 16 + cl];
        }
        const float b2v = ba2[nb * 16 + cl];
        f32x4 acc3 = {b2v, b2v, b2v, b2v};
        {
          const s16x8 b0 = *(const s16x8*)(sWa2B + ((0 * 8 + nb) * 64 + lane) * 8);
          const s16x8 b1 = *(const s16x8*)(sWa2B + ((1 * 8 + nb) * 64 + lane) * 8);
          acc3 = __builtin_amdgcn_mfma_f32_16x16x32_bf16(a3[0], b0, acc3, 0, 0, 0);
          acc3 = __builtin_amdgcn_mfma_f32_16x16x32_bf16(a3[1], b1, acc3, 0, 0, 0);
        }
        float x[4], y[4];
        #pragma unroll
        for (int i = 0; i < 4; ++i) {
          const float ee = __expf(fmaxf(acc3[i], 0.f));
          y[i] = ee;
          x[i] = ee * (hgc[i] + del[i]);
        }
        const float sx3 = x[3],                      sy3 = y[3];
        const float sx2 = x[2] + (eq23 ? sx3 : 0.f), sy2 = y[2] + (eq23 ? sy3 : 0.f);
        const float sx1 = x[1] + (eq12 ? sx2 : 0.f), sy1 = y[1] + (eq12 ? sy2 : 0.f);
        const float sx0 = x[0] + (eq01 ? sx1 : 0.f), sy0 = y[0] + (eq01 ? sy1 : 0.f);
        float Bx = 0.f, By = 0.f;
        #pragma unroll
        for (int tt = 0; tt < 3; ++tt) {
          const float nsx = __shfl_down(sx0, 16, 64);
          const float nsy = __shfl_down(sy0, 16, 64);
          const float nBx = __shfl_down(Bx, 16, 64);
          const float nBy = __shfl_down(By, 16, 64);
          Bx = cont ? (nsx + (fulln > 0.5f ? nBx : 0.f)) : 0.f;
          By = cont ? (nsy + (fulln > 0.5f ? nBy : 0.f)) : 0.f;
        }
        float hx[4], hy[4];
        #pragma unroll
        for (int i = 0; i < 4; ++i) {
          hx[i] = ((i == 0) ? sx0 : (i == 1) ? sx1 : (i == 2) ? sx2 : sx3) + (r_[i] ? Bx : 0.f);
          hy[i] = ((i == 0) ? sy0 : (i == 1) ? sy1 : (i == 2) ? sy2 : sy3) + (r_[i] ? By : 0.f);
        }
        const float h0x = __shfl(hx[0], cl, 64);
        const float h0y = __shfl(hy[0], cl, 64);
        if (mismatch && g == 0) {
          if (fo_final) {
            out[(size_t)oldd * 128 + nb * 16 + cl] = fmaxf(cX[nb] / (cY[nb] + 1e-16f), 0.f);
          } else {
            stag[(size_t)fo_slot * 256 + nb * 16 + cl] = cY[nb];
            stag[(size_t)fo_slot * 256 + 128 + nb * 16 + cl] = cX[nb];
          }
        }
        if (seed) { cX[nb] = h0x; cY[nb] = h0y; }
        else      { cX[nb] += h0x; cY[nb] += h0y; }
        if (closeFirst) {
          if (g == 0) {
            if (fc_final) {
              out[(size_t)f_d[q] * 128 + nb * 16 + cl] = fmaxf(cX[nb] / (cY[nb] + 1e-16f), 0.f);
            } else {
              stag[(size_t)fc_slot * 256 + nb * 16 + cl] = cY[nb];
              stag[(size_t)fc_slot * 256 + 128 + nb * 16 + cl] = cX[nb];
            }
          }
          #pragma unroll
          for (int i = 0; i < 4; ++i)
            if (fin[i])
              out[(size_t)dm[q][i] * 128 + nb * 16 + cl] = fmaxf(hx[i] / (hy[i] + 1e-16f), 0.f);
          const float selx = (i_h == 0) ? hx[0] : (i_h == 1) ? hx[1] : (i_h == 2) ? hx[2] : hx[3];
          const float sely = (i_h == 0) ? hy[0] : (i_h == 1) ? hy[1] : (i_h == 2) ? hy[2] : hy[3];
          cX[nb] = __shfl(selx, g_h * 16 + cl, 64);
          cY[nb] = __shfl(sely, g_h * 16 + cl, 64);
        }
      }
      carry_d = l_d[q];
    }
  }

  // wave-end flush
  {
    const int q0 = rowptr[carry_d], q1 = rowptr[carry_d + 1];
    const bool ffin = (q0 >= wb) && (q1 <= wb + 64);
    const int fslot = 2 * wid + ((q0 < wb) ? 0 : 1);
    if (g == 0) {
      #pragma unroll
      for (int nb = 0; nb < 8; ++nb) {
        if (ffin) {
          out[(size_t)carry_d * 128 + nb * 16 + cl] = fmaxf(cX[nb] / (cY[nb] + 1e-16f), 0.f);
        } else {
          stag[(size_t)fslot * 256 + nb * 16 + cl] = cY[nb];
          stag[(size_t)fslot * 256 + 128 + nb * 16 + cl] = cX[nb];
        }
      }
    }
  }
}

// ---------------- finalize: empty rows -> 0; spanning dsts -> sum staging ----------------
__global__ __launch_bounds__(256) void finalize_kernel(const int* __restrict__ rowptr,
                                                       const float* __restrict__ stag,
                                                       float* __restrict__ out) {
  const int idx = blockIdx.x * 256 + threadIdx.x;  // NN*32 threads
  const int d = idx >> 5;
  const int c4 = idx & 31;
  if (d >= NN) return;
  const int r0 = rowptr[d];
  const int r1 = rowptr[d + 1];
  float4* o4 = (float4*)(out + (size_t)d * 128 + c4 * 4);
  if (r0 == r1) {
    const float4 z = {0.f, 0.f, 0.f, 0.f};
    *o4 = z;
    return;
  }
  const int w0 = r0 >> 6;
  const int w1 = (r1 - 1) >> 6;
  if (w0 == w1) return;           // complete-in-wave: written by edge_mfma
  float ee0 = 0.f, ee1 = 0.f, ee2 = 0.f, ee3 = 0.f;
  float vv0 = 0.f, vv1 = 0.f, vv2 = 0.f, vv3 = 0.f;
  int slot = 2 * w0 + 1;
  for (int w = w0; w <= w1; ++w) {
    const float* sp = stag + (size_t)slot * 256;
    const float4 a = *(const float4*)(sp + c4 * 4);
    const float4 b = *(const float4*)(sp + 128 + c4 * 4);
    ee0 += a.x; ee1 += a.y; ee2 += a.z; ee3 += a.w;
    vv0 += b.x; vv1 += b.y; vv2 += b.z; vv3 += b.w;
    slot = 2 * (w + 1);
  }
  float4 r;
  r.x = fmaxf(vv0 / (ee0 + 1e-16f), 0.f);
  r.y = fmaxf(vv1 / (ee1 + 1e-16f), 0.f);
  r.z = fmaxf(vv2 / (ee2 + 1e-16f), 0.f);
  r.w = fmaxf(vv3 / (ee3 + 1e-16f), 0.f);
  *o4 = r;
}

extern "C" void kernel_launch(void* const* d_in, const int* in_sizes, int n_in,
                              void* d_out, int out_size, void* d_ws, size_t ws_size,
                              hipStream_t stream) {
  const float* x     = (const float*)d_in[0];
  const float* pos   = (const float*)d_in[1];
  const int*   ei    = (const int*)d_in[2];
  const float* W_lin = (const float*)d_in[3];
  const float* W_src = (const float*)d_in[4];
  const float* W_dst = (const float*)d_in[5];
  const float* Wp1   = (const float*)d_in[6];
  const float* bp1   = (const float*)d_in[7];
  const float* Wp2   = (const float*)d_in[8];
  const float* bp2   = (const float*)d_in[9];
  const float* Wa1   = (const float*)d_in[10];
  const float* ba1   = (const float*)d_in[11];
  const float* Wa2   = (const float*)d_in[12];
  const float* ba2   = (const float*)d_in[13];
  float* out = (float*)d_out;

  // workspace layout (~92 MB)
  float* h    = (float*)d_ws;                        // NN*128
  float* as1  = h   + (size_t)NN * 128;              // NN*64
  float* ad1  = as1 + (size_t)NN * 64;               // NN*64
  float* stag = ad1 + (size_t)NN * 64;               // 25000*256
  float* Wsa  = stag + (size_t)25000 * 256;          // 128*64
  float* Wda  = Wsa + 128 * 64;                      // 128*64
  unsigned short* W2B  = (unsigned short*)(Wda + 128 * 64);  // 8192
  unsigned short* Wa1B = W2B + 8192;                 // 8192
  unsigned short* Wa2B = Wa1B + 8192;                // 8192
  int* counts   = (int*)(Wa2B + 8192);               // NN
  int* ep       = counts + NN;
  int* cursor   = ep + NN;
  int* rowptr   = cursor + NN;                       // NN+1
  int* blocksum = rowptr + NN + 1;
  int* blockoff = blocksum + 196;
  int* ssrc     = blockoff + 196;                    // NE
  int* sdst     = ssrc + NE;                         // NE

  zero_counts<<<196, 256, 0, stream>>>(counts);
  count_fold_pack<<<3285, 256, 0, stream>>>(ei, counts, W_src, W_dst, Wa1,
                                            Wsa, Wda, Wp2, Wa2, W2B, Wa1B, Wa2B);
  scan_block<<<196, 256, 0, stream>>>(counts, ep, blocksum);
  scan_tops<<<1, 64, 0, stream>>>(blocksum, blockoff, 196);
  scan_finish<<<196, 256, 0, stream>>>(ep, blockoff, cursor, rowptr);
  scatter_gemm3<<<6250, 256, 0, stream>>>(ei, cursor, ssrc, sdst,
                                          x, W_lin, Wsa, Wda, h, as1, ad1);
  edge_mfma<<<3125, 256, 0, stream>>>(ssrc, sdst, rowptr, pos, h, as1, ad1,
                                      Wp1, bp1, W2B, bp2, Wa1B, ba1, Wa2B, ba2,
                                      out, stag);
  finalize_kernel<<<6250, 256, 0, stream>>>(rowptr, stag, out);
}

// Round 19
// 558.534 us; speedup vs baseline: 1.0687x; 1.0019x over previous
//
#include <hip/hip_runtime.h>
#include <hip/hip_bf16.h>

#define NN 50000
#define NE 800000

typedef short s16x8 __attribute__((ext_vector_type(8)));
typedef float f32x4 __attribute__((ext_vector_type(4)));

__device__ __forceinline__ unsigned packbf2(float a, float b) {
  __hip_bfloat162 h = __float22bfloat162_rn(make_float2(a, b));
  return *reinterpret_cast<unsigned*>(&h);
}
__device__ __forceinline__ unsigned short bf16rn(float x) {
  return (unsigned short)(packbf2(x, x) & 0xffffu);
}

// ---------------- zero counts ----------------
__global__ __launch_bounds__(256) void zero_counts(int* __restrict__ counts) {
  const int i = blockIdx.x * 256 + threadIdx.x;
  if (i < NN) counts[i] = 0;
}

// ---------------- fused: CSR count (3125 blocks) + fold_w (64) + pack_w (96) ----------------
__global__ __launch_bounds__(256) void count_fold_pack(
    const int* __restrict__ ei, int* __restrict__ counts,
    const float* __restrict__ Wsrc, const float* __restrict__ Wdst,
    const float* __restrict__ Wa1f,
    float* __restrict__ Wsa, float* __restrict__ Wda,
    const float* __restrict__ Wp2, const float* __restrict__ Wa2,
    unsigned short* __restrict__ W2B, unsigned short* __restrict__ Wa1B,
    unsigned short* __restrict__ Wa2B) {
  const int b = blockIdx.x;
  if (b < 3125) {                      // count
    const int e = b * 256 + threadIdx.x;
    if (e < NE) atomicAdd(&counts[ei[NE + e]], 1);
  } else if (b < 3125 + 64) {          // fold_w: Wsa = Wsrc@Wa1, Wda = Wdst@Wa1
    const int i = (b - 3125) * 256 + threadIdx.x;   // 16384 total
    const int m = i >> 13;
    const int kj = i & 8191;
    const int k = kj >> 6, j = kj & 63;
    const float* __restrict__ W = m ? Wdst : Wsrc;
    float acc = 0.f;
    #pragma unroll 4
    for (int q = 0; q < 128; ++q) acc = fmaf(W[k * 128 + q], Wa1f[q * 64 + j], acc);
    (m ? Wda : Wsa)[k * 64 + j] = acc;
  } else {                             // pack_w: B-frag order bf16
    const int t = (b - 3125 - 64) * 256 + threadIdx.x;  // 24576 total
    const int u = t & 8191;
    const int j = u & 7, l = (u >> 3) & 63;
    const int lk = (l >> 4) * 8 + j, ln = l & 15;
    if (t < 8192) {            // Wp2 [64][128]: 2 kb x 8 nb
      const int nb = (u >> 9) & 7, kb = u >> 12;
      W2B[u] = bf16rn(Wp2[(kb * 32 + lk) * 128 + nb * 16 + ln]);
    } else if (t < 16384) {    // Wa1 [128][64]: 4 kb x 4 nb
      const int nb = (u >> 9) & 3, kb = u >> 11;
      Wa1B[u] = bf16rn(Wa1f[(kb * 32 + lk) * 64 + nb * 16 + ln]);
    } else {                   // Wa2 [64][128]: 2 kb x 8 nb
      const int nb = (u >> 9) & 7, kb = u >> 12;
      Wa2B[u] = bf16rn(Wa2[(kb * 32 + lk) * 128 + nb * 16 + ln]);
    }
  }
}

__global__ __launch_bounds__(256) void scan_block(const int* __restrict__ counts,
                                                  int* __restrict__ ep,
                                                  int* __restrict__ blocksum) {
  const int i = blockIdx.x * 256 + threadIdx.x;
  const int lane = threadIdx.x & 63;
  const int w = threadIdx.x >> 6;
  const int v = (i < NN) ? counts[i] : 0;
  int s = v;
  #pragma unroll
  for (int off = 1; off < 64; off <<= 1) {
    const int t = __shfl_up(s, off, 64);
    if (lane >= off) s += t;
  }
  __shared__ int wsums[4];
  if (lane == 63) wsums[w] = s;
  __syncthreads();
  int add = 0;
  for (int j = 0; j < w; ++j) add += wsums[j];
  s += add;
  if (i < NN) ep[i] = s - v;
  if (threadIdx.x == 255) blocksum[blockIdx.x] = s;
}

__global__ void scan_tops(const int* __restrict__ blocksum,
                          int* __restrict__ blockoff, int n) {
  const int lane = threadIdx.x;
  int carry = 0;
  for (int base = 0; base < n; base += 64) {
    const int i = base + lane;
    const int v = (i < n) ? blocksum[i] : 0;
    int s = v;
    #pragma unroll
    for (int off = 1; off < 64; off <<= 1) {
      const int t = __shfl_up(s, off, 64);
      if (lane >= off) s += t;
    }
    s += carry;
    if (i < n) blockoff[i] = s - v;
    carry = __shfl(s, 63, 64);
  }
}

__global__ __launch_bounds__(256) void scan_finish(const int* __restrict__ ep,
                                                   const int* __restrict__ blockoff,
                                                   int* __restrict__ cursor,
                                                   int* __restrict__ rowptr) {
  const int i = blockIdx.x * 256 + threadIdx.x;
  if (i < NN) {
    const int v = ep[i] + blockoff[blockIdx.x];
    cursor[i] = v;
    rowptr[i] = v;
  }
  if (i == 0) rowptr[NN] = NE;
}

// ---------------- fused: scatter (3125 blocks) + node GEMMs (3125 blocks) ----------------
// scatter writes packed (src,dst) as one 8B store (half the scattered sectors)
__global__ __launch_bounds__(256) void scatter_gemm3(
    const int* __restrict__ ei, int* __restrict__ cursor,
    int2* __restrict__ sedge,
    const float* __restrict__ x, const float* __restrict__ Wl,
    const float* __restrict__ Wsa, const float* __restrict__ Wda,
    float* __restrict__ h, float* __restrict__ as1, float* __restrict__ ad1) {
  if (blockIdx.x < 3125) {             // scatter
    const int e = blockIdx.x * 256 + threadIdx.x;
    if (e < NE) {
      const int s = ei[e], d = ei[NE + e];
      const int p = atomicAdd(&cursor[d], 1);
      sedge[p] = make_int2(s, d);
    }
    return;
  }
  // gemm3
  const int wtask = __builtin_amdgcn_readfirstlane(
      (int)(((blockIdx.x - 3125) * 256 + threadIdx.x) >> 6));
  if (wtask >= 3125 * 4) return;
  const int lane = threadIdx.x & 63;
  const int rg = wtask >> 2;
  const int chunk = wtask & 3;
  const float* __restrict__ W = (chunk <= 1) ? Wl : ((chunk == 2) ? Wsa : Wda);
  float* __restrict__ O = (chunk <= 1) ? h : ((chunk == 2) ? as1 : ad1);
  const int ldw = (chunk <= 1) ? 128 : 64;
  const int col = ((chunk == 1) ? 64 : 0) + lane;
  const int r0 = rg * 16;
  float acc[16];
  #pragma unroll
  for (int r = 0; r < 16; ++r) acc[r] = 0.f;
  const float4* x4 = (const float4*)x;
  #pragma unroll 1
  for (int k4 = 0; k4 < 32; ++k4) {
    const float w0 = W[(size_t)(k4 * 4 + 0) * ldw + col];
    const float w1 = W[(size_t)(k4 * 4 + 1) * ldw + col];
    const float w2 = W[(size_t)(k4 * 4 + 2) * ldw + col];
    const float w3 = W[(size_t)(k4 * 4 + 3) * ldw + col];
    #pragma unroll
    for (int r = 0; r < 16; ++r) {
      const float4 xr = x4[(size_t)(r0 + r) * 32 + k4];
      acc[r] = fmaf(xr.x, w0, fmaf(xr.y, w1, fmaf(xr.z, w2, fmaf(xr.w, w3, acc[r]))));
    }
  }
  #pragma unroll
  for (int r = 0; r < 16; ++r) O[(size_t)(r0 + r) * ldw + col] = acc[r];
}

// ---------------- MFMA edge kernel (R18 pairwise-ILP + LDS weights + packed meta) ----------------
__global__ __launch_bounds__(256) void edge_mfma(
    const int2* __restrict__ sedge,
    const int* __restrict__ rowptr, const float* __restrict__ pos,
    const float* __restrict__ hbuf, const float* __restrict__ as1, const float* __restrict__ ad1,
    const float* __restrict__ Wp1, const float* __restrict__ bp1,
    const unsigned short* __restrict__ W2B, const float* __restrict__ bp2,
    const unsigned short* __restrict__ Wa1B, const float* __restrict__ ba1,
    const unsigned short* __restrict__ Wa2B, const float* __restrict__ ba2,
    float* __restrict__ out, float* __restrict__ stag) {
  __shared__ uint4 ldsq[4][768];   // 12KB/wave: region q at q*6144: [0,4096) delta, [4096,6144) ha
  __shared__ unsigned short sW2B[8192], sWa1B[8192], sWa2B[8192];  // 48KB weights
  {
    const uint4* g0 = (const uint4*)W2B;
    const uint4* g1 = (const uint4*)Wa1B;
    const uint4* g2 = (const uint4*)Wa2B;
    uint4* t0 = (uint4*)sW2B;
    uint4* t1 = (uint4*)sWa1B;
    uint4* t2 = (uint4*)sWa2B;
    #pragma unroll
    for (int k = 0; k < 4; ++k) {
      const int idx = k * 256 + threadIdx.x;
      t0[idx] = g0[idx];
      t1[idx] = g1[idx];
      t2[idx] = g2[idx];
    }
  }
  __syncthreads();

  const int wv = threadIdx.x >> 6;
  char* lb0 = (char*)&ldsq[wv][0];
  const int lane = threadIdx.x & 63;
  const int g = lane >> 4;
  const int cl = lane & 15;
  const int wid = blockIdx.x * 4 + wv;
  const int wb = wid * 64;

  float cX[8], cY[8];
  #pragma unroll
  for (int nb = 0; nb < 8; ++nb) { cX[nb] = 0.f; cY[nb] = 0.f; }
  int carry_d = -1;

  #pragma unroll 1
  for (int p = 0; p < 2; ++p) {
    // ---- meta both subtiles (single 8B load each) ----
    int myS[2], myD[2];
    {
      const int2 e0 = sedge[wb + p * 32 + cl];
      const int2 e1 = sedge[wb + p * 32 + 16 + cl];
      myS[0] = e0.x; myD[0] = e0.y;
      myS[1] = e1.x; myD[1] = e1.y;
    }
    int dm[2][4], sm[2][4], f_d[2], l_d[2];
    #pragma unroll
    for (int q = 0; q < 2; ++q) {
      #pragma unroll
      for (int i = 0; i < 4; ++i) {
        dm[q][i] = __shfl(myD[q], 4 * g + i, 64);
        sm[q][i] = __shfl(myS[q], 4 * g + i, 64);
      }
      f_d[q] = __shfl(myD[q], 0, 64);
      l_d[q] = __shfl(myD[q], 15, 64);
    }

    // ---- gDiff both subtiles: 16 loads in flight ----
    float gDiff[2][4][4];
    #pragma unroll
    for (int q = 0; q < 2; ++q) {
      #pragma unroll
      for (int i = 0; i < 4; ++i) {
        #pragma unroll
        for (int nb = 0; nb < 4; ++nb) {
          gDiff[q][i][nb] = ad1[(size_t)dm[q][i] * 64 + nb * 16 + cl]
                          - as1[(size_t)sm[q][i] * 64 + nb * 16 + cl];
        }
      }
    }

    // ---- hd -> A1 frags, both subtiles ----
    s16x8 a1[2][2];
    #pragma unroll
    for (int q = 0; q < 2; ++q) {
      const float2 pD = ((const float2*)pos)[myD[q]];
      const float2 pS = ((const float2*)pos)[myS[q]];
      const float p0 = pD.x - pS.x, p1 = pD.y - pS.y;
      #pragma unroll
      for (int kb = 0; kb < 2; ++kb) {
        const int k0 = kb * 32 + g * 8;
        const float4 wA = *(const float4*)(Wp1 + k0);
        const float4 wB = *(const float4*)(Wp1 + k0 + 4);
        const float4 vA = *(const float4*)(Wp1 + 64 + k0);
        const float4 vB = *(const float4*)(Wp1 + 64 + k0 + 4);
        const float4 bA = *(const float4*)(bp1 + k0);
        const float4 bB = *(const float4*)(bp1 + k0 + 4);
        float f0 = fmaxf(fmaf(p0, wA.x, fmaf(p1, vA.x, bA.x)), 0.f);
        float f1 = fmaxf(fmaf(p0, wA.y, fmaf(p1, vA.y, bA.y)), 0.f);
        float f2 = fmaxf(fmaf(p0, wA.z, fmaf(p1, vA.z, bA.z)), 0.f);
        float f3 = fmaxf(fmaf(p0, wA.w, fmaf(p1, vA.w, bA.w)), 0.f);
        float f4 = fmaxf(fmaf(p0, wB.x, fmaf(p1, vB.x, bB.x)), 0.f);
        float f5 = fmaxf(fmaf(p0, wB.y, fmaf(p1, vB.y, bB.y)), 0.f);
        float f6 = fmaxf(fmaf(p0, wB.z, fmaf(p1, vB.z, bB.z)), 0.f);
        float f7 = fmaxf(fmaf(p0, wB.w, fmaf(p1, vB.w, bB.w)), 0.f);
        uint4 qq;
        qq.x = packbf2(f0, f1); qq.y = packbf2(f2, f3);
        qq.z = packbf2(f4, f5); qq.w = packbf2(f6, f7);
        a1[q][kb] = __builtin_bit_cast(s16x8, qq);
      }
    }

    // ---- GEMM1 both subtiles -> own LDS delta regions ----
    #pragma unroll
    for (int q = 0; q < 2; ++q) {
      char* lbq = lb0 + q * 6144;
      #pragma unroll
      for (int nb = 0; nb < 8; ++nb) {
        const float bias = bp2[nb * 16 + cl];
        f32x4 acc = {bias, bias, bias, bias};
        const s16x8 b0 = *(const s16x8*)(sW2B + ((0 * 8 + nb) * 64 + lane) * 8);
        const s16x8 b1 = *(const s16x8*)(sW2B + ((1 * 8 + nb) * 64 + lane) * 8);
        acc = __builtin_amdgcn_mfma_f32_16x16x32_bf16(a1[q][0], b0, acc, 0, 0, 0);
        acc = __builtin_amdgcn_mfma_f32_16x16x32_bf16(a1[q][1], b1, acc, 0, 0, 0);
        #pragma unroll
        for (int i = 0; i < 4; ++i) {
          const int row = g * 4 + i;
          const int byt = (row << 8) + ((((nb * 16 + cl) * 2)) ^ ((row & 7) << 5));
          *(unsigned short*)(lbq + byt) = bf16rn(fmaxf(acc[i], 0.f));
        }
      }
    }

    // ---- A2 + GEMM2 both subtiles -> own LDS ha regions ----
    #pragma unroll
    for (int q = 0; q < 2; ++q) {
      char* lbq = lb0 + q * 6144;
      s16x8 a2[4];
      #pragma unroll
      for (int kb = 0; kb < 4; ++kb) {
        const int byt = (cl << 8) + ((kb * 64 + g * 16) ^ ((cl & 7) << 5));
        a2[kb] = __builtin_bit_cast(s16x8, *(const uint4*)(lbq + byt));
      }
      #pragma unroll
      for (int nb = 0; nb < 4; ++nb) {
        const float b1v = ba1[nb * 16 + cl];
        f32x4 acc = {gDiff[q][0][nb] + b1v, gDiff[q][1][nb] + b1v,
                     gDiff[q][2][nb] + b1v, gDiff[q][3][nb] + b1v};
        #pragma unroll
        for (int kb = 0; kb < 4; ++kb) {
          const s16x8 b = *(const s16x8*)(sWa1B + ((kb * 4 + nb) * 64 + lane) * 8);
          acc = __builtin_amdgcn_mfma_f32_16x16x32_bf16(a2[kb], b, acc, 0, 0, 0);
        }
        #pragma unroll
        for (int i = 0; i < 4; ++i) {
          const int row = g * 4 + i;
          const int byt = 4096 + (row << 7) + ((((nb * 16 + cl) * 2)) ^ ((row & 7) << 4));
          *(unsigned short*)(lbq + byt) = bf16rn(fmaxf(acc[i], 0.f));
        }
      }
    }

    // ---- per-subtile GEMM3 + epilogue (sequential: carry chain) ----
    #pragma unroll
    for (int q = 0; q < 2; ++q) {
      char* lbq = lb0 + q * 6144;
      s16x8 a3[2];
      #pragma unroll
      for (int kb = 0; kb < 2; ++kb) {
        const int byt = 4096 + (cl << 7) + ((kb * 64 + g * 16) ^ ((cl & 7) << 4));
        a3[kb] = __builtin_bit_cast(s16x8, *(const uint4*)(lbq + byt));
      }

      const bool eq01 = dm[q][0] == dm[q][1], eq12 = dm[q][1] == dm[q][2],
                 eq23 = dm[q][2] == dm[q][3];
      bool r_[4];
      r_[3] = true; r_[2] = eq23; r_[1] = eq12 && eq23; r_[0] = eq01 && eq12 && eq23;
      const int dnx = __shfl(myD[q], (4 * g + 4) & 15, 64);
      const bool cont = (g < 3) && (dm[q][3] == dnx);
      const float fullf = r_[0] ? 1.f : 0.f;
      const float fulln = __shfl_down(fullf, 16, 64);
      const int dpv = __shfl(myD[q], (4 * g - 1) & 15, 64);
      bool head[4];
      head[0] = (g == 0) ? true : (dm[q][0] != dpv);
      head[1] = dm[q][1] != dm[q][0];
      head[2] = dm[q][2] != dm[q][1];
      head[3] = dm[q][3] != dm[q][2];
      bool fin[4];
      #pragma unroll
      for (int i = 0; i < 4; ++i)
        fin[i] = head[i] && !(g == 0 && i == 0) && (dm[q][i] != l_d[q]);

      const int st = p * 2 + q;
      const bool mismatch = (st != 0) && (carry_d != f_d[q]);
      const bool seed = (st == 0) || mismatch;
      const bool closeFirst = (f_d[q] != l_d[q]);
      const int oldd = carry_d;
      int fo_final = 0, fo_slot = 0;
      if (mismatch) {
        const int q0 = rowptr[oldd], q1 = rowptr[oldd + 1];
        if (q0 >= wb && q1 <= wb + 64) fo_final = 1;
        else fo_slot = 2 * wid + ((q0 < wb) ? 0 : 1);
      }
      int fc_final = 0, fc_slot = 0;
      if (closeFirst) {
        const int q0 = rowptr[f_d[q]], q1 = rowptr[f_d[q] + 1];
        if (q0 >= wb && q1 <= wb + 64) fc_final = 1;
        else fc_slot = 2 * wid + ((q0 < wb) ? 0 : 1);
      }
      const unsigned long long bal = __ballot(myD[q] == l_d[q]);
      const int m_h = (int)__builtin_ctzll(bal & 0xffffull);
      const int i_h = m_h & 3, g_h = m_h >> 2;

      float hgn[4];
      #pragma unroll
      for (int i = 0; i < 4; ++i) hgn[i] = hbuf[(size_t)sm[q][i] * 128 + cl];  // nb=0
      #pragma unroll
      for (int nb = 0; nb < 8; ++nb) {
        float del[4];
        #pragma unroll
        for (int i = 0; i < 4; ++i) {
          const int row = g * 4 + i;
          const int byt = (row << 8) + ((((nb * 16 + cl) * 2)) ^ ((row & 7) << 5));
          const unsigned short uu = *(const unsigned short*)(lbq + byt);
          del[i] = __builtin_bit_cast(float, ((unsigned)uu) << 16);
        }
        float hgc[4];
        #pragma unroll
        for (int i = 0; i < 4; ++i) hgc[i] = hgn[i];
        if (nb < 7) {
          #pragma unroll
          for (int i = 0; i < 4; ++i)
            hgn[i] = hbuf[(size_t)sm[q][i] * 128 + (nb + 1) * 16 + cl];
        }
        const float b2v = ba2[nb * 16 + cl];
        f32x4 acc3 = {b2v, b2v, b2v, b2v};
        {
          const s16x8 b0 = *(const s16x8*)(sWa2B + ((0 * 8 + nb) * 64 + lane) * 8);
          const s16x8 b1 = *(const s16x8*)(sWa2B + ((1 * 8 + nb) * 64 + lane) * 8);
          acc3 = __builtin_amdgcn_mfma_f32_16x16x32_bf16(a3[0], b0, acc3, 0, 0, 0);
          acc3 = __builtin_amdgcn_mfma_f32_16x16x32_bf16(a3[1], b1, acc3, 0, 0, 0);
        }
        float x[4], y[4];
        #pragma unroll
        for (int i = 0; i < 4; ++i) {
          const float ee = __expf(fmaxf(acc3[i], 0.f));
          y[i] = ee;
          x[i] = ee * (hgc[i] + del[i]);
        }
        const float sx3 = x[3],                      sy3 = y[3];
        const float sx2 = x[2] + (eq23 ? sx3 : 0.f), sy2 = y[2] + (eq23 ? sy3 : 0.f);
        const float sx1 = x[1] + (eq12 ? sx2 : 0.f), sy1 = y[1] + (eq12 ? sy2 : 0.f);
        const float sx0 = x[0] + (eq01 ? sx1 : 0.f), sy0 = y[0] + (eq01 ? sy1 : 0.f);
        float Bx = 0.f, By = 0.f;
        #pragma unroll
        for (int tt = 0; tt < 3; ++tt) {
          const float nsx = __shfl_down(sx0, 16, 64);
          const float nsy = __shfl_down(sy0, 16, 64);
          const float nBx = __shfl_down(Bx, 16, 64);
          const float nBy = __shfl_down(By, 16, 64);
          Bx = cont ? (nsx + (fulln > 0.5f ? nBx : 0.f)) : 0.f;
          By = cont ? (nsy + (fulln > 0.5f ? nBy : 0.f)) : 0.f;
        }
        float hx[4], hy[4];
        #pragma unroll
        for (int i = 0; i < 4; ++i) {
          hx[i] = ((i == 0) ? sx0 : (i == 1) ? sx1 : (i == 2) ? sx2 : sx3) + (r_[i] ? Bx : 0.f);
          hy[i] = ((i == 0) ? sy0 : (i == 1) ? sy1 : (i == 2) ? sy2 : sy3) + (r_[i] ? By : 0.f);
        }
        const float h0x = __shfl(hx[0], cl, 64);
        const float h0y = __shfl(hy[0], cl, 64);
        if (mismatch && g == 0) {
          if (fo_final) {
            out[(size_t)oldd * 128 + nb * 16 + cl] = fmaxf(cX[nb] / (cY[nb] + 1e-16f), 0.f);
          } else {
            stag[(size_t)fo_slot * 256 + nb * 16 + cl] = cY[nb];
            stag[(size_t)fo_slot * 256 + 128 + nb * 16 + cl] = cX[nb];
          }
        }
        if (seed) { cX[nb] = h0x; cY[nb] = h0y; }
        else      { cX[nb] += h0x; cY[nb] += h0y; }
        if (closeFirst) {
          if (g == 0) {
            if (fc_final) {
              out[(size_t)f_d[q] * 128 + nb * 16 + cl] = fmaxf(cX[nb] / (cY[nb] + 1e-16f), 0.f);
            } else {
              stag[(size_t)fc_slot * 256 + nb * 16 + cl] = cY[nb];
              stag[(size_t)fc_slot * 256 + 128 + nb * 16 + cl] = cX[nb];
            }
          }
          #pragma unroll
          for (int i = 0; i < 4; ++i)
            if (fin[i])
              out[(size_t)dm[q][i] * 128 + nb * 16 + cl] = fmaxf(hx[i] / (hy[i] + 1e-16f), 0.f);
          const float selx = (i_h == 0) ? hx[0] : (i_h == 1) ? hx[1] : (i_h == 2) ? hx[2] : hx[3];
          const float sely = (i_h == 0) ? hy[0] : (i_h == 1) ? hy[1] : (i_h == 2) ? hy[2] : hy[3];
          cX[nb] = __shfl(selx, g_h * 16 + cl, 64);
          cY[nb] = __shfl(sely, g_h * 16 + cl, 64);
        }
      }
      carry_d = l_d[q];
    }
  }

  // wave-end flush
  {
    const int q0 = rowptr[carry_d], q1 = rowptr[carry_d + 1];
    const bool ffin = (q0 >= wb) && (q1 <= wb + 64);
    const int fslot = 2 * wid + ((q0 < wb) ? 0 : 1);
    if (g == 0) {
      #pragma unroll
      for (int nb = 0; nb < 8; ++nb) {
        if (ffin) {
          out[(size_t)carry_d * 128 + nb * 16 + cl] = fmaxf(cX[nb] / (cY[nb] + 1e-16f), 0.f);
        } else {
          stag[(size_t)fslot * 256 + nb * 16 + cl] = cY[nb];
          stag[(size_t)fslot * 256 + 128 + nb * 16 + cl] = cX[nb];
        }
      }
    }
  }
}

// ---------------- finalize: empty rows -> 0; spanning dsts -> sum staging ----------------
__global__ __launch_bounds__(256) void finalize_kernel(const int* __restrict__ rowptr,
                                                       const float* __restrict__ stag,
                                                       float* __restrict__ out) {
  const int idx = blockIdx.x * 256 + threadIdx.x;  // NN*32 threads
  const int d = idx >> 5;
  const int c4 = idx & 31;
  if (d >= NN) return;
  const int r0 = rowptr[d];
  const int r1 = rowptr[d + 1];
  float4* o4 = (float4*)(out + (size_t)d * 128 + c4 * 4);
  if (r0 == r1) {
    const float4 z = {0.f, 0.f, 0.f, 0.f};
    *o4 = z;
    return;
  }
  const int w0 = r0 >> 6;
  const int w1 = (r1 - 1) >> 6;
  if (w0 == w1) return;           // complete-in-wave: written by edge_mfma
  float ee0 = 0.f, ee1 = 0.f, ee2 = 0.f, ee3 = 0.f;
  float vv0 = 0.f, vv1 = 0.f, vv2 = 0.f, vv3 = 0.f;
  int slot = 2 * w0 + 1;
  for (int w = w0; w <= w1; ++w) {
    const float* sp = stag + (size_t)slot * 256;
    const float4 a = *(const float4*)(sp + c4 * 4);
    const float4 b = *(const float4*)(sp + 128 + c4 * 4);
    ee0 += a.x; ee1 += a.y; ee2 += a.z; ee3 += a.w;
    vv0 += b.x; vv1 += b.y; vv2 += b.z; vv3 += b.w;
    slot = 2 * (w + 1);
  }
  float4 r;
  r.x = fmaxf(vv0 / (ee0 + 1e-16f), 0.f);
  r.y = fmaxf(vv1 / (ee1 + 1e-16f), 0.f);
  r.z = fmaxf(vv2 / (ee2 + 1e-16f), 0.f);
  r.w = fmaxf(vv3 / (ee3 + 1e-16f), 0.f);
  *o4 = r;
}

extern "C" void kernel_launch(void* const* d_in, const int* in_sizes, int n_in,
                              void* d_out, int out_size, void* d_ws, size_t ws_size,
                              hipStream_t stream) {
  const float* x     = (const float*)d_in[0];
  const float* pos   = (const float*)d_in[1];
  const int*   ei    = (const int*)d_in[2];
  const float* W_lin = (const float*)d_in[3];
  const float* W_src = (const float*)d_in[4];
  const float* W_dst = (const float*)d_in[5];
  const float* Wp1   = (const float*)d_in[6];
  const float* bp1   = (const float*)d_in[7];
  const float* Wp2   = (const float*)d_in[8];
  const float* bp2   = (const float*)d_in[9];
  const float* Wa1   = (const float*)d_in[10];
  const float* ba1   = (const float*)d_in[11];
  const float* Wa2   = (const float*)d_in[12];
  const float* ba2   = (const float*)d_in[13];
  float* out = (float*)d_out;

  // workspace layout (~92 MB)
  float* h    = (float*)d_ws;                        // NN*128
  float* as1  = h   + (size_t)NN * 128;              // NN*64
  float* ad1  = as1 + (size_t)NN * 64;               // NN*64
  float* stag = ad1 + (size_t)NN * 64;               // 25000*256
  float* Wsa  = stag + (size_t)25000 * 256;          // 128*64
  float* Wda  = Wsa + 128 * 64;                      // 128*64
  unsigned short* W2B  = (unsigned short*)(Wda + 128 * 64);  // 8192
  unsigned short* Wa1B = W2B + 8192;                 // 8192
  unsigned short* Wa2B = Wa1B + 8192;                // 8192
  int* counts   = (int*)(Wa2B + 8192);               // NN
  int* ep       = counts + NN;
  int* cursor   = ep + NN;
  int* rowptr   = cursor + NN;                       // NN+1
  int* blocksum = rowptr + NN + 1;
  int* blockoff = blocksum + 196;
  int2* sedge   = (int2*)(((uintptr_t)(blockoff + 196) + 7) & ~(uintptr_t)7);  // NE int2

  zero_counts<<<196, 256, 0, stream>>>(counts);
  count_fold_pack<<<3285, 256, 0, stream>>>(ei, counts, W_src, W_dst, Wa1,
                                            Wsa, Wda, Wp2, Wa2, W2B, Wa1B, Wa2B);
  scan_block<<<196, 256, 0, stream>>>(counts, ep, blocksum);
  scan_tops<<<1, 64, 0, stream>>>(blocksum, blockoff, 196);
  scan_finish<<<196, 256, 0, stream>>>(ep, blockoff, cursor, rowptr);
  scatter_gemm3<<<6250, 256, 0, stream>>>(ei, cursor, sedge,
                                          x, W_lin, Wsa, Wda, h, as1, ad1);
  edge_mfma<<<3125, 256, 0, stream>>>(sedge, rowptr, pos, h, as1, ad1,
                                      Wp1, bp1, W2B, bp2, Wa1B, ba1, Wa2B, ba2,
                                      out, stag);
  finalize_kernel<<<6250, 256, 0, stream>>>(rowptr, stag, out);
}